// Round 9
// baseline (296.771 us; speedup 1.0000x reference)
//
#include <hip/hip_runtime.h>

#define VOCAB 50000
#define VDIM 256
#define TOPICS 512
#define VT 32
#define NBLK 1563   // ceil(VOCAB/VT)

typedef unsigned int uint;
typedef unsigned short ushort;
using short8 = __attribute__((ext_vector_type(8))) short;
using f32x4  = __attribute__((ext_vector_type(4))) float;

__device__ __forceinline__ ushort bf16_rne(float f) {
  uint u = __float_as_uint(f);
  u += 0x7FFFu + ((u >> 16) & 1u);
  return (ushort)(u >> 16);
}
__device__ __forceinline__ float bf16f(ushort h) {
  return __uint_as_float(((uint)h) << 16);
}
__device__ __forceinline__ uint packbf2(float a, float b) {
  return (uint)bf16_rne(a) | ((uint)bf16_rne(b) << 16);
}

// ---------------------------------------------------------------------------
// Precompute with fragment-major packing (hi/lo bf16 split):
//   tBp[tile=t>>4][ks=d>>5][hl][lane=(t&15)|(((d>>3)&3)<<4)][e=d&7]
//   Atp[dtile=d>>4][ks=t>>5][hl][lane=(d&15)|(((t>>3)&3)<<4)][e=t&7]
// Each wave-load in fused_main is one coalesced 1KB dwordx4.
// ---------------------------------------------------------------------------
__global__ __launch_bounds__(512) void precompute(
    const float* __restrict__ t2v, const float* __restrict__ A,
    const float* __restrict__ B,
    ushort* __restrict__ tBp, ushort* __restrict__ Atp)
{
  __shared__ float row[256];
  const int b = blockIdx.x, tid = threadIdx.x;
  if (b < TOPICS) {
    const int t = b;
    if (tid < 256) row[tid] = t2v[(size_t)t * 256 + tid];
    __syncthreads();
    if (tid < 256) {
      const int d = tid;
      const float4* rv = (const float4*)row;
      const float4* bv = (const float4*)(B + (size_t)d * 256);
      float acc = 0.f;
#pragma unroll 8
      for (int k = 0; k < 64; ++k) {
        float4 r = rv[k], x = bv[k];
        acc += r.x * x.x + r.y * x.y + r.z * x.z + r.w * x.w;
      }
      ushort hi = bf16_rne(acc);
      ushort lo = bf16_rne(acc - bf16f(hi));
      const int tile = t >> 4, ks = d >> 5;
      const int lane = (t & 15) | (((d >> 3) & 3) << 4);
      const int e = d & 7;
      size_t base = ((size_t)(tile * 8 + ks) * 2) * 512 + lane * 8 + e;
      tBp[base]       = hi;
      tBp[base + 512] = lo;
    }
  } else {
    const int d = b - TOPICS;
    if (tid < 256) row[tid] = A[(size_t)d * 256 + tid];
    __syncthreads();
    const int t = tid;
    const float4* rv = (const float4*)row;
    const float4* tv = (const float4*)(t2v + (size_t)t * 256);
    float acc = 0.f;
#pragma unroll 8
    for (int k = 0; k < 64; ++k) {
      float4 r = rv[k], x = tv[k];
      acc += r.x * x.x + r.y * x.y + r.z * x.z + r.w * x.w;
    }
    ushort hi = bf16_rne(acc);
    ushort lo = bf16_rne(acc - bf16f(hi));
    const int dtile = d >> 4, ks = t >> 5;
    const int lane = (d & 15) | (((t >> 3) & 3) << 4);
    const int e = t & 7;
    size_t base = ((size_t)(dtile * 16 + ks) * 2) * 512 + lane * 8 + e;
    Atp[base]       = hi;
    Atp[base + 512] = lo;
  }
}

// ---------------------------------------------------------------------------
// Fused main — R8 structure, ONLY change: A-fragment register rings deepened
// to a full K-step (depth 8 = 16 loads in flight per wave), prefetch distance
// ~24 MFMAs > L2/L3 latency. Slot index == mi (fully static).
// ---------------------------------------------------------------------------
__global__ __launch_bounds__(256, 4) void fused_main(
    const float* __restrict__ w2v,
    const ushort* __restrict__ tBp, const ushort* __restrict__ Atp,
    const float* __restrict__ sigma,
    float* __restrict__ out_alpha, float* __restrict__ out_P,
    float* __restrict__ out_s,
    float* __restrict__ part_rs, float* __restrict__ part_ss, int do_rl)
{
  __shared__ __align__(16) char smem[33792];
  ushort (*Whi)[264] = (ushort (*)[264])smem;            // 16896 B
  ushort (*Wlo)[264] = (ushort (*)[264])(smem + 16896);  // 16896 B
  ushort (*PA)[520]  = (ushort (*)[520])smem;            // 33280 B (alias, W dead)
  __shared__ float red[4][VT];
  __shared__ float rs_lds[TOPICS];                       // 2 KB rowsum stage

  const int tid  = threadIdx.x;
  const int wave = tid >> 6, lane = tid & 63;
  const int lr = lane & 15, lg = lane >> 4;
  const int vb = blockIdx.x * VT;

  // ---- issue FULL first K-step of A-fragments (16 loads) before staging ----
  const ushort* sbase = tBp + (size_t)wave * 65536 + lane * 8;
  short8 Ah[8], Al[8];
#pragma unroll
  for (int i = 0; i < 8; ++i) {              // steps 0..7 (ks = 0, mi = i)
    Ah[i] = *(const short8*)(sbase + (size_t)i * 8192);
    Al[i] = *(const short8*)(sbase + (size_t)i * 8192 + 512);
  }

  // ---- stage W hi/lo (32 rows x 256 dims) ----
#pragma unroll
  for (int it = 0; it < 8; ++it) {
    int j = tid + (it << 8);
    int v = j >> 6, q = j & 63;
    int vr = min(vb + v, VOCAB - 1);
    float4 x = *(const float4*)(w2v + (size_t)vr * 256 + (q << 2));
    float xs[4] = {x.x, x.y, x.z, x.w};
    ushort h[4], l[4];
#pragma unroll
    for (int i = 0; i < 4; ++i) {
      ushort hi = bf16_rne(xs[i]);
      h[i] = hi;
      l[i] = bf16_rne(xs[i] - bf16f(hi));
    }
    *(uint2*)&Whi[v][q << 2] = make_uint2((uint)h[0] | ((uint)h[1] << 16),
                                          (uint)h[2] | ((uint)h[3] << 16));
    *(uint2*)&Wlo[v][q << 2] = make_uint2((uint)l[0] | ((uint)l[1] << 16),
                                          (uint)l[2] | ((uint)l[3] << 16));
  }
  __syncthreads();

  // ---- s-GEMM: flattened 64 steps (ks=n>>3, mi=n&7), depth-8 ring ----
  f32x4 acc[8][2];
#pragma unroll
  for (int mi = 0; mi < 8; ++mi)
#pragma unroll
    for (int nj = 0; nj < 2; ++nj) acc[mi][nj] = (f32x4){0.f, 0.f, 0.f, 0.f};

  short8 Bh[2][2], Bl[2][2];
  {
    const int k0 = lg << 3;
    Bh[0][0] = *(const short8*)&Whi[lr][k0];
    Bh[0][1] = *(const short8*)&Whi[16 + lr][k0];
    Bl[0][0] = *(const short8*)&Wlo[lr][k0];
    Bl[0][1] = *(const short8*)&Wlo[16 + lr][k0];
  }

#pragma unroll
  for (int n = 0; n < 64; ++n) {
    const int ks = n >> 3, mi = n & 7, cs = ks & 1;
    if (mi == 0 && ks < 7) {      // B-frags for next ks, one full ks ahead
      const int k0 = ((ks + 1) << 5) + (lg << 3);
      Bh[cs ^ 1][0] = *(const short8*)&Whi[lr][k0];
      Bh[cs ^ 1][1] = *(const short8*)&Whi[16 + lr][k0];
      Bl[cs ^ 1][0] = *(const short8*)&Wlo[lr][k0];
      Bl[cs ^ 1][1] = *(const short8*)&Wlo[16 + lr][k0];
    }
    short8 ah = Ah[mi], al = Al[mi];
    if (n + 8 < 64) {             // refill slot mi with step n+8 (same mi)
      const ushort* p = sbase + (size_t)mi * 8192 + (size_t)(ks + 1) * 1024;
      Ah[mi] = *(const short8*)p;
      Al[mi] = *(const short8*)(p + 512);
    }
#pragma unroll
    for (int nj = 0; nj < 2; ++nj) {
      acc[mi][nj] = __builtin_amdgcn_mfma_f32_16x16x32_bf16(ah, Bh[cs][nj], acc[mi][nj], 0, 0, 0);
      acc[mi][nj] = __builtin_amdgcn_mfma_f32_16x16x32_bf16(al, Bh[cs][nj], acc[mi][nj], 0, 0, 0);
      acc[mi][nj] = __builtin_amdgcn_mfma_f32_16x16x32_bf16(ah, Bl[cs][nj], acc[mi][nj], 0, 0, 0);
    }
  }

  // ---- write s (D layout: col = lr, row = lg*4 + r) ----
#pragma unroll
  for (int mi = 0; mi < 8; ++mi) {
    const int t = (wave << 7) + (mi << 4) + (lg << 2);
#pragma unroll
    for (int r = 0; r < 4; ++r)
#pragma unroll
      for (int nj = 0; nj < 2; ++nj) {
        const int v = vb + (nj << 4) + lr;
        if (v < VOCAB) out_s[(size_t)(t + r) * VOCAB + v] = acc[mi][nj][r];
      }
  }

  // ---- softmax over t per column ----
  float gmax[2];
  {
    float pm[2] = {-3.4e38f, -3.4e38f};
#pragma unroll
    for (int mi = 0; mi < 8; ++mi)
#pragma unroll
      for (int nj = 0; nj < 2; ++nj)
#pragma unroll
        for (int r = 0; r < 4; ++r) pm[nj] = fmaxf(pm[nj], acc[mi][nj][r]);
#pragma unroll
    for (int nj = 0; nj < 2; ++nj) {
      pm[nj] = fmaxf(pm[nj], __shfl_xor(pm[nj], 16));
      pm[nj] = fmaxf(pm[nj], __shfl_xor(pm[nj], 32));
    }
    if (lg == 0) { red[wave][lr] = pm[0]; red[wave][16 + lr] = pm[1]; }
  }
  __syncthreads();
#pragma unroll
  for (int nj = 0; nj < 2; ++nj) {
    const int c = (nj << 4) + lr;
    gmax[nj] = fmaxf(fmaxf(red[0][c], red[1][c]), fmaxf(red[2][c], red[3][c]));
  }
  __syncthreads();

  // ---- issue FULL first 2 mu K-steps of A-fragments (16 loads) now; they
  //      hide under the exp pass + two barriers ----
  const ushort* mbase = Atp + (size_t)wave * 65536 + lane * 8;
  short8 Mh[8], Ml[8];
#pragma unroll
  for (int i = 0; i < 8; ++i) {              // steps 0..7 = ks 0..1, mi = i&3
    const ushort* p = mbase + (size_t)(i & 3) * 16384 + (size_t)(i >> 2) * 1024;
    Mh[i] = *(const short8*)p;
    Ml[i] = *(const short8*)(p + 512);
  }

  float inv[2];
  {
    float ps[2] = {0.f, 0.f};
#pragma unroll
    for (int mi = 0; mi < 8; ++mi)
#pragma unroll
      for (int nj = 0; nj < 2; ++nj)
#pragma unroll
        for (int r = 0; r < 4; ++r) {
          float e = __expf(acc[mi][nj][r] - gmax[nj]);
          acc[mi][nj][r] = e;
          ps[nj] += e;
        }
#pragma unroll
    for (int nj = 0; nj < 2; ++nj) {
      ps[nj] += __shfl_xor(ps[nj], 16);
      ps[nj] += __shfl_xor(ps[nj], 32);
    }
    if (lg == 0) { red[wave][lr] = ps[0]; red[wave][16 + lr] = ps[1]; }
  }
  __syncthreads();
#pragma unroll
  for (int nj = 0; nj < 2; ++nj) {
    const int c = (nj << 4) + lr;
    inv[nj] = 1.0f / (red[0][c] + red[1][c] + red[2][c] + red[3][c]);
  }
  __syncthreads();   // red reads done; last Whi/Wlo reads were in s-loop

  // ---- alpha = exp*inv: fp32 to global, bf16 to LDS (PA aliases W),
  //      rowsum partials into rs_lds (no global scatter) ----
  float ssq = 0.f;
#pragma unroll
  for (int mi = 0; mi < 8; ++mi) {
    const int tb = (wave << 7) + (mi << 4) + (lg << 2);
#pragma unroll
    for (int nj = 0; nj < 2; ++nj) {
#pragma unroll
      for (int r = 0; r < 4; ++r) acc[mi][nj][r] *= inv[nj];
      const int v = vb + (nj << 4) + lr;
      if (v < VOCAB) {
#pragma unroll
        for (int r = 0; r < 4; ++r)
          out_alpha[(size_t)(tb + r) * VOCAB + v] = acc[mi][nj][r];
      }
      uint2 pw;
      pw.x = packbf2(acc[mi][nj][0], acc[mi][nj][1]);
      pw.y = packbf2(acc[mi][nj][2], acc[mi][nj][3]);
      *(uint2*)&PA[(nj << 4) + lr][tb] = pw;
    }
    if (do_rl) {
#pragma unroll
      for (int r = 0; r < 4; ++r) {
        float rowp = 0.f;
#pragma unroll
        for (int nj = 0; nj < 2; ++nj) {
          float a = acc[mi][nj][r];
          float am = (vb + (nj << 4) + lr < VOCAB) ? a : 0.f;
          rowp += am;
          ssq = fmaf(am, am, ssq);
        }
        rowp += __shfl_xor(rowp, 1);
        rowp += __shfl_xor(rowp, 2);
        rowp += __shfl_xor(rowp, 4);
        rowp += __shfl_xor(rowp, 8);
        if (lr == 0) rs_lds[tb + r] = rowp;
      }
    }
  }
  __syncthreads();

  // ---- mu-GEMM: flattened 64 steps (ks=n>>2, mi=n&3), depth-8 ring ----
  f32x4 macc[4][2];
#pragma unroll
  for (int mi = 0; mi < 4; ++mi)
#pragma unroll
    for (int nj = 0; nj < 2; ++nj) macc[mi][nj] = (f32x4){0.f, 0.f, 0.f, 0.f};

  short8 Pb[2][2];
  {
    const int k0 = lg << 3;
    Pb[0][0] = *(const short8*)&PA[lr][k0];
    Pb[0][1] = *(const short8*)&PA[16 + lr][k0];
  }
#pragma unroll
  for (int n = 0; n < 64; ++n) {
    const int ks = n >> 2, mi = n & 3, cs = ks & 1;
    if (mi == 0 && ks < 15) {
      const int k0 = ((ks + 1) << 5) + (lg << 3);
      Pb[cs ^ 1][0] = *(const short8*)&PA[lr][k0];
      Pb[cs ^ 1][1] = *(const short8*)&PA[16 + lr][k0];
    }
    short8 ah = Mh[n & 7], al = Ml[n & 7];
    if (n + 8 < 64) {             // refill slot (n&7) with step n+8
      const int n8 = n + 8;
      const ushort* p = mbase + (size_t)(n8 & 3) * 16384 + (size_t)(n8 >> 2) * 1024;
      Mh[n & 7] = *(const short8*)p;
      Ml[n & 7] = *(const short8*)(p + 512);
    }
#pragma unroll
    for (int nj = 0; nj < 2; ++nj) {
      macc[mi][nj] = __builtin_amdgcn_mfma_f32_16x16x32_bf16(ah, Pb[cs][nj], macc[mi][nj], 0, 0, 0);
      macc[mi][nj] = __builtin_amdgcn_mfma_f32_16x16x32_bf16(al, Pb[cs][nj], macc[mi][nj], 0, 0, 0);
    }
  }

  // ---- P: sum_d (w2v - mu)^2 per column (w2v re-read from global/L2) ----
  {
    float pp[2] = {0.f, 0.f};
#pragma unroll
    for (int mi = 0; mi < 4; ++mi) {
      const int dbase = (wave << 6) + (mi << 4) + (lg << 2);
#pragma unroll
      for (int nj = 0; nj < 2; ++nj) {
        const int vr = min(vb + (nj << 4) + lr, VOCAB - 1);
        float4 w = *(const float4*)(w2v + (size_t)vr * 256 + dbase);
        float d0 = w.x - macc[mi][nj][0];
        float d1 = w.y - macc[mi][nj][1];
        float d2 = w.z - macc[mi][nj][2];
        float d3 = w.w - macc[mi][nj][3];
        pp[nj] += d0 * d0 + d1 * d1 + d2 * d2 + d3 * d3;
      }
    }
#pragma unroll
    for (int nj = 0; nj < 2; ++nj) {
      pp[nj] += __shfl_xor(pp[nj], 16);
      pp[nj] += __shfl_xor(pp[nj], 32);
    }
    if (lg == 0) { red[wave][lr] = pp[0]; red[wave][16 + lr] = pp[1]; }
  }
  __syncthreads();
  if (tid < VT) {
    float sum = red[0][tid] + red[1][tid] + red[2][tid] + red[3][tid];
    const int v = vb + tid;
    if (v < VOCAB) out_P[v] = sum / sigma[0];
  }

  // ---- coalesced part_rs block store (2KB contiguous) + ssq ----
  if (do_rl) {
    part_rs[(size_t)blockIdx.x * TOPICS + tid]       = rs_lds[tid];
    part_rs[(size_t)blockIdx.x * TOPICS + 256 + tid] = rs_lds[256 + tid];
    ssq += __shfl_xor(ssq, 1);
    ssq += __shfl_xor(ssq, 2);
    ssq += __shfl_xor(ssq, 4);
    ssq += __shfl_xor(ssq, 8);
    ssq += __shfl_xor(ssq, 16);
    ssq += __shfl_xor(ssq, 32);
    if (lane == 0) part_ss[blockIdx.x * 4 + wave] = ssq;
  }
}

// ---------------------------------------------------------------------------
// RL pass 2: rowsum[t] = sum_blk part_rs[blk][t]. One block per topic.
// ---------------------------------------------------------------------------
__global__ __launch_bounds__(256) void rl_pass2(
    const float* __restrict__ part_rs, float* __restrict__ rowsum)
{
  const int t = blockIdx.x;
  float s = 0.f;
  for (int i = threadIdx.x; i < NBLK; i += 256)
    s += part_rs[(size_t)i * TOPICS + t];
  __shared__ float lsum[4];
  const int lane = threadIdx.x & 63, wave = threadIdx.x >> 6;
#pragma unroll
  for (int off = 32; off > 0; off >>= 1) s += __shfl_xor(s, off);
  if (lane == 0) lsum[wave] = s;
  __syncthreads();
  if (threadIdx.x == 0) rowsum[t] = lsum[0] + lsum[1] + lsum[2] + lsum[3];
}

// RL finalize: RL = sum part_ss - sum_t rowsum^2 / VOCAB
__global__ __launch_bounds__(512) void rl_final_new(
    const float* __restrict__ rowsum, const float* __restrict__ part_ss,
    const float* __restrict__ sigma, float* __restrict__ out_RL,
    float* __restrict__ out_sigma)
{
  const int t = threadIdx.x;
  float b = rowsum[t] * rowsum[t];
  float a = 0.f;
  for (int i = t; i < NBLK * 4; i += 512) a += part_ss[i];
  __shared__ float la[8], lb[8];
  const int lane = t & 63, wave = t >> 6;
#pragma unroll
  for (int off = 32; off > 0; off >>= 1) {
    a += __shfl_xor(a, off);
    b += __shfl_xor(b, off);
  }
  if (lane == 0) { la[wave] = a; lb[wave] = b; }
  __syncthreads();
  if (t == 0) {
    float sa = 0.f, sb = 0.f;
#pragma unroll
    for (int w = 0; w < 8; ++w) { sa += la[w]; sb += lb[w]; }
    out_RL[0] = sa - sb / (float)VOCAB;
    out_sigma[0] = sigma[0];
  }
}

// ---------------------------------------------------------------------------
// Fallback (small ws): old alpha re-read path
// ---------------------------------------------------------------------------
__global__ __launch_bounds__(256) void row_reduce(
    const float* __restrict__ alpha, float* __restrict__ rowsum, float* __restrict__ ssum)
{
  const int t = blockIdx.x;
  const float4* base = (const float4*)(alpha + (size_t)t * VOCAB);
  float rs = 0.f, ss = 0.f;
  for (int i = threadIdx.x; i < VOCAB / 4; i += 256) {
    float4 a = base[i];
    rs += a.x + a.y + a.z + a.w;
    ss += a.x * a.x + a.y * a.y + a.z * a.z + a.w * a.w;
  }
  __shared__ float lr[4], ls[4];
  const int lane = threadIdx.x & 63, wave = threadIdx.x >> 6;
#pragma unroll
  for (int off = 32; off > 0; off >>= 1) {
    rs += __shfl_xor(rs, off);
    ss += __shfl_xor(ss, off);
  }
  if (lane == 0) { lr[wave] = rs; ls[wave] = ss; }
  __syncthreads();
  if (threadIdx.x == 0) {
    rowsum[t] = lr[0] + lr[1] + lr[2] + lr[3];
    ssum[t]   = ls[0] + ls[1] + ls[2] + ls[3];
  }
}

__global__ __launch_bounds__(512) void rl_final_old(
    const float* __restrict__ rowsum, const float* __restrict__ ssum,
    const float* __restrict__ sigma, float* __restrict__ out_RL,
    float* __restrict__ out_sigma)
{
  const int t = threadIdx.x;
  float a = ssum[t];
  float b = rowsum[t] * rowsum[t];
  __shared__ float la[8], lb[8];
  const int lane = t & 63, wave = t >> 6;
#pragma unroll
  for (int off = 32; off > 0; off >>= 1) {
    a += __shfl_xor(a, off);
    b += __shfl_xor(b, off);
  }
  if (lane == 0) { la[wave] = a; lb[wave] = b; }
  __syncthreads();
  if (t == 0) {
    float sa = 0.f, sb = 0.f;
#pragma unroll
    for (int w = 0; w < 8; ++w) { sa += la[w]; sb += lb[w]; }
    out_RL[0] = sa - sb / (float)VOCAB;
    out_sigma[0] = sigma[0];
  }
}

extern "C" void kernel_launch(void* const* d_in, const int* in_sizes, int n_in,
                              void* d_out, int out_size, void* d_ws, size_t ws_size,
                              hipStream_t stream) {
  const float* w2v   = (const float*)d_in[0];  // [50000][256]
  const float* t2v   = (const float*)d_in[1];  // [512][256]
  const float* A     = (const float*)d_in[2];  // [256][256]
  const float* B     = (const float*)d_in[3];  // [256][256]
  const float* sigma = (const float*)d_in[4];  // [1]

  float* out       = (float*)d_out;
  float* out_alpha = out;                                  // 25,600,000
  float* out_P     = out + (size_t)TOPICS * VOCAB;         // 50,000
  float* out_RL    = out_P + VOCAB;                        // 1
  float* out_s     = out_RL + 1;                           // 25,600,000
  float* out_sigma = out_s + (size_t)TOPICS * VOCAB;       // 1

  ushort* tBp = (ushort*)d_ws;                             // 262144 ushorts
  ushort* Atp = tBp + (size_t)262144;                      // 262144 ushorts
  float* tail = (float*)(Atp + (size_t)262144);            // after 1 MiB
  float* part_rs = tail;                                   // [NBLK][512]
  float* part_ss = part_rs + (size_t)NBLK * TOPICS;        // 1563*4
  float* rowsum  = part_ss + (size_t)NBLK * 4;             // 512
  size_t need = (size_t)(2 * 262144) * 2 +
                ((size_t)NBLK * TOPICS + (size_t)NBLK * 4 + TOPICS) * 4;
  const int do_rl = (ws_size >= need) ? 1 : 0;

  precompute<<<TOPICS + VDIM, 512, 0, stream>>>(t2v, A, B, tBp, Atp);

  fused_main<<<NBLK, 256, 0, stream>>>(w2v, tBp, Atp, sigma,
                                       out_alpha, out_P, out_s,
                                       part_rs, part_ss, do_rl);

  if (do_rl) {
    rl_pass2<<<TOPICS, 256, 0, stream>>>(part_rs, rowsum);
    rl_final_new<<<1, 512, 0, stream>>>(rowsum, part_ss, sigma, out_RL, out_sigma);
  } else {
    float* rs_old = tail;
    float* ss_old = rs_old + TOPICS;
    row_reduce<<<TOPICS, 256, 0, stream>>>(out_alpha, rs_old, ss_old);
    rl_final_old<<<1, 512, 0, stream>>>(rs_old, ss_old, sigma, out_RL, out_sigma);
  }
}

// Round 10
// 284.395 us; speedup vs baseline: 1.0435x; 1.0435x over previous
//
#include <hip/hip_runtime.h>

#define VOCAB 50000
#define VDIM 256
#define TOPICS 512
#define VT 32
#define NBLK 1563   // ceil(VOCAB/VT)

typedef unsigned int uint;
typedef unsigned short ushort;
using short8 = __attribute__((ext_vector_type(8))) short;
using f32x4  = __attribute__((ext_vector_type(4))) float;

__device__ __forceinline__ ushort bf16_rne(float f) {
  uint u = __float_as_uint(f);
  u += 0x7FFFu + ((u >> 16) & 1u);
  return (ushort)(u >> 16);
}
__device__ __forceinline__ float bf16f(ushort h) {
  return __uint_as_float(((uint)h) << 16);
}
__device__ __forceinline__ uint packbf2(float a, float b) {
  return (uint)bf16_rne(a) | ((uint)bf16_rne(b) << 16);
}

// ---------------------------------------------------------------------------
// Precompute with fragment-major packing (hi/lo bf16 split):
//   tBp[tile=t>>4][ks=d>>5][hl][lane=(t&15)|(((d>>3)&3)<<4)][e=d&7]
//   Atp[dtile=d>>4][ks=t>>5][hl][lane=(d&15)|(((t>>3)&3)<<4)][e=t&7]
// Each wave-load in fused_main is one coalesced 1KB dwordx4.
// ---------------------------------------------------------------------------
__global__ __launch_bounds__(512) void precompute(
    const float* __restrict__ t2v, const float* __restrict__ A,
    const float* __restrict__ B,
    ushort* __restrict__ tBp, ushort* __restrict__ Atp)
{
  __shared__ float row[256];
  const int b = blockIdx.x, tid = threadIdx.x;
  if (b < TOPICS) {
    const int t = b;
    if (tid < 256) row[tid] = t2v[(size_t)t * 256 + tid];
    __syncthreads();
    if (tid < 256) {
      const int d = tid;
      const float4* rv = (const float4*)row;
      const float4* bv = (const float4*)(B + (size_t)d * 256);
      float acc = 0.f;
#pragma unroll 8
      for (int k = 0; k < 64; ++k) {
        float4 r = rv[k], x = bv[k];
        acc += r.x * x.x + r.y * x.y + r.z * x.z + r.w * x.w;
      }
      ushort hi = bf16_rne(acc);
      ushort lo = bf16_rne(acc - bf16f(hi));
      const int tile = t >> 4, ks = d >> 5;
      const int lane = (t & 15) | (((d >> 3) & 3) << 4);
      const int e = d & 7;
      size_t base = ((size_t)(tile * 8 + ks) * 2) * 512 + lane * 8 + e;
      tBp[base]       = hi;
      tBp[base + 512] = lo;
    }
  } else {
    const int d = b - TOPICS;
    if (tid < 256) row[tid] = A[(size_t)d * 256 + tid];
    __syncthreads();
    const int t = tid;
    const float4* rv = (const float4*)row;
    const float4* tv = (const float4*)(t2v + (size_t)t * 256);
    float acc = 0.f;
#pragma unroll 8
    for (int k = 0; k < 64; ++k) {
      float4 r = rv[k], x = tv[k];
      acc += r.x * x.x + r.y * x.y + r.z * x.z + r.w * x.w;
    }
    ushort hi = bf16_rne(acc);
    ushort lo = bf16_rne(acc - bf16f(hi));
    const int dtile = d >> 4, ks = t >> 5;
    const int lane = (d & 15) | (((t >> 3) & 3) << 4);
    const int e = t & 7;
    size_t base = ((size_t)(dtile * 16 + ks) * 2) * 512 + lane * 8 + e;
    Atp[base]       = hi;
    Atp[base + 512] = lo;
  }
}

// ---------------------------------------------------------------------------
// Fused main — EXACT R8 structure; ONLY change: all pure-streaming global
// stores (s, alpha, part_rs) are NON-TEMPORAL so the ~300MB store stream
// does not evict the 1MB tBp/Atp read panels from the XCD L2.
// ---------------------------------------------------------------------------
__global__ __launch_bounds__(256, 4) void fused_main(
    const float* __restrict__ w2v,
    const ushort* __restrict__ tBp, const ushort* __restrict__ Atp,
    const float* __restrict__ sigma,
    float* __restrict__ out_alpha, float* __restrict__ out_P,
    float* __restrict__ out_s,
    float* __restrict__ part_rs, float* __restrict__ part_ss, int do_rl)
{
  __shared__ __align__(16) char smem[33792];
  ushort (*Whi)[264] = (ushort (*)[264])smem;            // 16896 B
  ushort (*Wlo)[264] = (ushort (*)[264])(smem + 16896);  // 16896 B
  ushort (*PA)[520]  = (ushort (*)[520])smem;            // 33280 B (alias, W dead)
  __shared__ float red[4][VT];
  __shared__ float rs_lds[TOPICS];                       // 2 KB rowsum stage

  const int tid  = threadIdx.x;
  const int wave = tid >> 6, lane = tid & 63;
  const int lr = lane & 15, lg = lane >> 4;
  const int vb = blockIdx.x * VT;

  // ---- stage W hi/lo (32 rows x 256 dims) ----
#pragma unroll
  for (int it = 0; it < 8; ++it) {
    int j = tid + (it << 8);
    int v = j >> 6, q = j & 63;
    int vr = min(vb + v, VOCAB - 1);
    float4 x = *(const float4*)(w2v + (size_t)vr * 256 + (q << 2));
    float xs[4] = {x.x, x.y, x.z, x.w};
    ushort h[4], l[4];
#pragma unroll
    for (int i = 0; i < 4; ++i) {
      ushort hi = bf16_rne(xs[i]);
      h[i] = hi;
      l[i] = bf16_rne(xs[i] - bf16f(hi));
    }
    *(uint2*)&Whi[v][q << 2] = make_uint2((uint)h[0] | ((uint)h[1] << 16),
                                          (uint)h[2] | ((uint)h[3] << 16));
    *(uint2*)&Wlo[v][q << 2] = make_uint2((uint)l[0] | ((uint)l[1] << 16),
                                          (uint)l[2] | ((uint)l[3] << 16));
  }
  __syncthreads();

  // ---- s-GEMM: acc[mi][nj], t-rows = wave*128 + mi*16 + lr ----
  f32x4 acc[8][2];
#pragma unroll
  for (int mi = 0; mi < 8; ++mi)
#pragma unroll
    for (int nj = 0; nj < 2; ++nj) acc[mi][nj] = (f32x4){0.f, 0.f, 0.f, 0.f};

#pragma unroll
  for (int ks = 0; ks < 8; ++ks) {
    const int k0 = (ks << 5) + (lg << 3);
    short8 bh[2], bl[2];
#pragma unroll
    for (int nj = 0; nj < 2; ++nj) {
      bh[nj] = *(const short8*)&Whi[(nj << 4) + lr][k0];
      bl[nj] = *(const short8*)&Wlo[(nj << 4) + lr][k0];
    }
    // packed A base: tile = wave*8 + mi; stride per tile = 8192 ushorts
    const ushort* abase = tBp + ((size_t)(wave * 8) * 8 + ks) * 1024 + lane * 8;
    short8 ahp[2], alp[2];
    ahp[0] = *(const short8*)(abase);
    alp[0] = *(const short8*)(abase + 512);
    ahp[1] = *(const short8*)(abase + 8192);
    alp[1] = *(const short8*)(abase + 8192 + 512);
#pragma unroll
    for (int mi = 0; mi < 8; ++mi) {
      short8 ah = ahp[mi & 1], al = alp[mi & 1];
      if (mi < 6) {
        ahp[mi & 1] = *(const short8*)(abase + (size_t)(mi + 2) * 8192);
        alp[mi & 1] = *(const short8*)(abase + (size_t)(mi + 2) * 8192 + 512);
      }
#pragma unroll
      for (int nj = 0; nj < 2; ++nj) {
        acc[mi][nj] = __builtin_amdgcn_mfma_f32_16x16x32_bf16(ah, bh[nj], acc[mi][nj], 0, 0, 0);
        acc[mi][nj] = __builtin_amdgcn_mfma_f32_16x16x32_bf16(al, bh[nj], acc[mi][nj], 0, 0, 0);
        acc[mi][nj] = __builtin_amdgcn_mfma_f32_16x16x32_bf16(ah, bl[nj], acc[mi][nj], 0, 0, 0);
      }
    }
  }

  // ---- write s (non-temporal: streaming, never re-read) ----
#pragma unroll
  for (int mi = 0; mi < 8; ++mi) {
    const int t = (wave << 7) + (mi << 4) + (lg << 2);
#pragma unroll
    for (int r = 0; r < 4; ++r)
#pragma unroll
      for (int nj = 0; nj < 2; ++nj) {
        const int v = vb + (nj << 4) + lr;
        if (v < VOCAB)
          __builtin_nontemporal_store(acc[mi][nj][r],
                                      out_s + (size_t)(t + r) * VOCAB + v);
      }
  }

  // ---- softmax over t per column ----
  float gmax[2];
  {
    float pm[2] = {-3.4e38f, -3.4e38f};
#pragma unroll
    for (int mi = 0; mi < 8; ++mi)
#pragma unroll
      for (int nj = 0; nj < 2; ++nj)
#pragma unroll
        for (int r = 0; r < 4; ++r) pm[nj] = fmaxf(pm[nj], acc[mi][nj][r]);
#pragma unroll
    for (int nj = 0; nj < 2; ++nj) {
      pm[nj] = fmaxf(pm[nj], __shfl_xor(pm[nj], 16));
      pm[nj] = fmaxf(pm[nj], __shfl_xor(pm[nj], 32));
    }
    if (lg == 0) { red[wave][lr] = pm[0]; red[wave][16 + lr] = pm[1]; }
  }
  __syncthreads();
#pragma unroll
  for (int nj = 0; nj < 2; ++nj) {
    const int c = (nj << 4) + lr;
    gmax[nj] = fmaxf(fmaxf(red[0][c], red[1][c]), fmaxf(red[2][c], red[3][c]));
  }
  __syncthreads();

  float inv[2];
  {
    float ps[2] = {0.f, 0.f};
#pragma unroll
    for (int mi = 0; mi < 8; ++mi)
#pragma unroll
      for (int nj = 0; nj < 2; ++nj)
#pragma unroll
        for (int r = 0; r < 4; ++r) {
          float e = __expf(acc[mi][nj][r] - gmax[nj]);
          acc[mi][nj][r] = e;
          ps[nj] += e;
        }
#pragma unroll
    for (int nj = 0; nj < 2; ++nj) {
      ps[nj] += __shfl_xor(ps[nj], 16);
      ps[nj] += __shfl_xor(ps[nj], 32);
    }
    if (lg == 0) { red[wave][lr] = ps[0]; red[wave][16 + lr] = ps[1]; }
  }
  __syncthreads();
#pragma unroll
  for (int nj = 0; nj < 2; ++nj) {
    const int c = (nj << 4) + lr;
    inv[nj] = 1.0f / (red[0][c] + red[1][c] + red[2][c] + red[3][c]);
  }
  __syncthreads();   // red reads done; last Whi/Wlo reads were in s-loop

  // ---- alpha = exp*inv: fp32 NT to global, bf16 to LDS (PA aliases W),
  //      rowsum partials into rs_lds (no global scatter) ----
  float ssq = 0.f;
#pragma unroll
  for (int mi = 0; mi < 8; ++mi) {
    const int tb = (wave << 7) + (mi << 4) + (lg << 2);
#pragma unroll
    for (int nj = 0; nj < 2; ++nj) {
#pragma unroll
      for (int r = 0; r < 4; ++r) acc[mi][nj][r] *= inv[nj];
      const int v = vb + (nj << 4) + lr;
      if (v < VOCAB) {
#pragma unroll
        for (int r = 0; r < 4; ++r)
          __builtin_nontemporal_store(acc[mi][nj][r],
                                      out_alpha + (size_t)(tb + r) * VOCAB + v);
      }
      uint2 pw;
      pw.x = packbf2(acc[mi][nj][0], acc[mi][nj][1]);
      pw.y = packbf2(acc[mi][nj][2], acc[mi][nj][3]);
      *(uint2*)&PA[(nj << 4) + lr][tb] = pw;
    }
    if (do_rl) {
#pragma unroll
      for (int r = 0; r < 4; ++r) {
        float rowp = 0.f;
#pragma unroll
        for (int nj = 0; nj < 2; ++nj) {
          float a = acc[mi][nj][r];
          float am = (vb + (nj << 4) + lr < VOCAB) ? a : 0.f;
          rowp += am;
          ssq = fmaf(am, am, ssq);
        }
        rowp += __shfl_xor(rowp, 1);
        rowp += __shfl_xor(rowp, 2);
        rowp += __shfl_xor(rowp, 4);
        rowp += __shfl_xor(rowp, 8);
        if (lr == 0) rs_lds[tb + r] = rowp;
      }
    }
  }
  __syncthreads();

  // ---- mu-GEMM: macc[mi][nj], d-rows = wave*64 + mi*16 + lr, K=512 ----
  f32x4 macc[4][2];
#pragma unroll
  for (int mi = 0; mi < 4; ++mi)
#pragma unroll
    for (int nj = 0; nj < 2; ++nj) macc[mi][nj] = (f32x4){0.f, 0.f, 0.f, 0.f};

#pragma unroll
  for (int ks = 0; ks < 16; ++ks) {
    const int k0 = (ks << 5) + (lg << 3);
    short8 pb[2];
#pragma unroll
    for (int nj = 0; nj < 2; ++nj)
      pb[nj] = *(const short8*)&PA[(nj << 4) + lr][k0];
    // packed At base: dtile = wave*4 + mi; stride per dtile = 16384 ushorts
    const ushort* abase = Atp + ((size_t)(wave * 4) * 16 + ks) * 1024 + lane * 8;
    short8 ahp[2], alp[2];
    ahp[0] = *(const short8*)(abase);
    alp[0] = *(const short8*)(abase + 512);
    ahp[1] = *(const short8*)(abase + 16384);
    alp[1] = *(const short8*)(abase + 16384 + 512);
#pragma unroll
    for (int mi = 0; mi < 4; ++mi) {
      short8 ah = ahp[mi & 1], al = alp[mi & 1];
      if (mi < 2) {
        ahp[mi & 1] = *(const short8*)(abase + (size_t)(mi + 2) * 16384);
        alp[mi & 1] = *(const short8*)(abase + (size_t)(mi + 2) * 16384 + 512);
      }
#pragma unroll
      for (int nj = 0; nj < 2; ++nj) {
        macc[mi][nj] = __builtin_amdgcn_mfma_f32_16x16x32_bf16(ah, pb[nj], macc[mi][nj], 0, 0, 0);
        macc[mi][nj] = __builtin_amdgcn_mfma_f32_16x16x32_bf16(al, pb[nj], macc[mi][nj], 0, 0, 0);
      }
    }
  }

  // ---- P: sum_d (w2v - mu)^2 per column (w2v re-read from global/L2) ----
  {
    float pp[2] = {0.f, 0.f};
#pragma unroll
    for (int mi = 0; mi < 4; ++mi) {
      const int dbase = (wave << 6) + (mi << 4) + (lg << 2);
#pragma unroll
      for (int nj = 0; nj < 2; ++nj) {
        const int vr = min(vb + (nj << 4) + lr, VOCAB - 1);
        float4 w = *(const float4*)(w2v + (size_t)vr * 256 + dbase);
        float d0 = w.x - macc[mi][nj][0];
        float d1 = w.y - macc[mi][nj][1];
        float d2 = w.z - macc[mi][nj][2];
        float d3 = w.w - macc[mi][nj][3];
        pp[nj] += d0 * d0 + d1 * d1 + d2 * d2 + d3 * d3;
      }
    }
#pragma unroll
    for (int nj = 0; nj < 2; ++nj) {
      pp[nj] += __shfl_xor(pp[nj], 16);
      pp[nj] += __shfl_xor(pp[nj], 32);
    }
    if (lg == 0) { red[wave][lr] = pp[0]; red[wave][16 + lr] = pp[1]; }
  }
  __syncthreads();
  if (tid < VT) {
    float sum = red[0][tid] + red[1][tid] + red[2][tid] + red[3][tid];
    const int v = vb + tid;
    if (v < VOCAB) out_P[v] = sum / sigma[0];
  }

  // ---- coalesced part_rs block store (2KB contiguous, NT) + ssq ----
  if (do_rl) {
    __builtin_nontemporal_store(rs_lds[tid],
                                part_rs + (size_t)blockIdx.x * TOPICS + tid);
    __builtin_nontemporal_store(rs_lds[256 + tid],
                                part_rs + (size_t)blockIdx.x * TOPICS + 256 + tid);
    ssq += __shfl_xor(ssq, 1);
    ssq += __shfl_xor(ssq, 2);
    ssq += __shfl_xor(ssq, 4);
    ssq += __shfl_xor(ssq, 8);
    ssq += __shfl_xor(ssq, 16);
    ssq += __shfl_xor(ssq, 32);
    if (lane == 0) part_ss[blockIdx.x * 4 + wave] = ssq;
  }
}

// ---------------------------------------------------------------------------
// RL pass 2: rowsum[t] = sum_blk part_rs[blk][t]. One block per topic.
// ---------------------------------------------------------------------------
__global__ __launch_bounds__(256) void rl_pass2(
    const float* __restrict__ part_rs, float* __restrict__ rowsum)
{
  const int t = blockIdx.x;
  float s = 0.f;
  for (int i = threadIdx.x; i < NBLK; i += 256)
    s += part_rs[(size_t)i * TOPICS + t];
  __shared__ float lsum[4];
  const int lane = threadIdx.x & 63, wave = threadIdx.x >> 6;
#pragma unroll
  for (int off = 32; off > 0; off >>= 1) s += __shfl_xor(s, off);
  if (lane == 0) lsum[wave] = s;
  __syncthreads();
  if (threadIdx.x == 0) rowsum[t] = lsum[0] + lsum[1] + lsum[2] + lsum[3];
}

// RL finalize: RL = sum part_ss - sum_t rowsum^2 / VOCAB
__global__ __launch_bounds__(512) void rl_final_new(
    const float* __restrict__ rowsum, const float* __restrict__ part_ss,
    const float* __restrict__ sigma, float* __restrict__ out_RL,
    float* __restrict__ out_sigma)
{
  const int t = threadIdx.x;
  float b = rowsum[t] * rowsum[t];
  float a = 0.f;
  for (int i = t; i < NBLK * 4; i += 512) a += part_ss[i];
  __shared__ float la[8], lb[8];
  const int lane = t & 63, wave = t >> 6;
#pragma unroll
  for (int off = 32; off > 0; off >>= 1) {
    a += __shfl_xor(a, off);
    b += __shfl_xor(b, off);
  }
  if (lane == 0) { la[wave] = a; lb[wave] = b; }
  __syncthreads();
  if (t == 0) {
    float sa = 0.f, sb = 0.f;
#pragma unroll
    for (int w = 0; w < 8; ++w) { sa += la[w]; sb += lb[w]; }
    out_RL[0] = sa - sb / (float)VOCAB;
    out_sigma[0] = sigma[0];
  }
}

// ---------------------------------------------------------------------------
// Fallback (small ws): old alpha re-read path
// ---------------------------------------------------------------------------
__global__ __launch_bounds__(256) void row_reduce(
    const float* __restrict__ alpha, float* __restrict__ rowsum, float* __restrict__ ssum)
{
  const int t = blockIdx.x;
  const float4* base = (const float4*)(alpha + (size_t)t * VOCAB);
  float rs = 0.f, ss = 0.f;
  for (int i = threadIdx.x; i < VOCAB / 4; i += 256) {
    float4 a = base[i];
    rs += a.x + a.y + a.z + a.w;
    ss += a.x * a.x + a.y * a.y + a.z * a.z + a.w * a.w;
  }
  __shared__ float lr[4], ls[4];
  const int lane = threadIdx.x & 63, wave = threadIdx.x >> 6;
#pragma unroll
  for (int off = 32; off > 0; off >>= 1) {
    rs += __shfl_xor(rs, off);
    ss += __shfl_xor(ss, off);
  }
  if (lane == 0) { lr[wave] = rs; ls[wave] = ss; }
  __syncthreads();
  if (threadIdx.x == 0) {
    rowsum[t] = lr[0] + lr[1] + lr[2] + lr[3];
    ssum[t]   = ls[0] + ls[1] + ls[2] + ls[3];
  }
}

__global__ __launch_bounds__(512) void rl_final_old(
    const float* __restrict__ rowsum, const float* __restrict__ ssum,
    const float* __restrict__ sigma, float* __restrict__ out_RL,
    float* __restrict__ out_sigma)
{
  const int t = threadIdx.x;
  float a = ssum[t];
  float b = rowsum[t] * rowsum[t];
  __shared__ float la[8], lb[8];
  const int lane = t & 63, wave = t >> 6;
#pragma unroll
  for (int off = 32; off > 0; off >>= 1) {
    a += __shfl_xor(a, off);
    b += __shfl_xor(b, off);
  }
  if (lane == 0) { la[wave] = a; lb[wave] = b; }
  __syncthreads();
  if (t == 0) {
    float sa = 0.f, sb = 0.f;
#pragma unroll
    for (int w = 0; w < 8; ++w) { sa += la[w]; sb += lb[w]; }
    out_RL[0] = sa - sb / (float)VOCAB;
    out_sigma[0] = sigma[0];
  }
}

extern "C" void kernel_launch(void* const* d_in, const int* in_sizes, int n_in,
                              void* d_out, int out_size, void* d_ws, size_t ws_size,
                              hipStream_t stream) {
  const float* w2v   = (const float*)d_in[0];  // [50000][256]
  const float* t2v   = (const float*)d_in[1];  // [512][256]
  const float* A     = (const float*)d_in[2];  // [256][256]
  const float* B     = (const float*)d_in[3];  // [256][256]
  const float* sigma = (const float*)d_in[4];  // [1]

  float* out       = (float*)d_out;
  float* out_alpha = out;                                  // 25,600,000
  float* out_P     = out + (size_t)TOPICS * VOCAB;         // 50,000
  float* out_RL    = out_P + VOCAB;                        // 1
  float* out_s     = out_RL + 1;                           // 25,600,000
  float* out_sigma = out_s + (size_t)TOPICS * VOCAB;       // 1

  ushort* tBp = (ushort*)d_ws;                             // 262144 ushorts
  ushort* Atp = tBp + (size_t)262144;                      // 262144 ushorts
  float* tail = (float*)(Atp + (size_t)262144);            // after 1 MiB
  float* part_rs = tail;                                   // [NBLK][512]
  float* part_ss = part_rs + (size_t)NBLK * TOPICS;        // 1563*4
  float* rowsum  = part_ss + (size_t)NBLK * 4;             // 512
  size_t need = (size_t)(2 * 262144) * 2 +
                ((size_t)NBLK * TOPICS + (size_t)NBLK * 4 + TOPICS) * 4;
  const int do_rl = (ws_size >= need) ? 1 : 0;

  precompute<<<TOPICS + VDIM, 512, 0, stream>>>(t2v, A, B, tBp, Atp);

  fused_main<<<NBLK, 256, 0, stream>>>(w2v, tBp, Atp, sigma,
                                       out_alpha, out_P, out_s,
                                       part_rs, part_ss, do_rl);

  if (do_rl) {
    rl_pass2<<<TOPICS, 256, 0, stream>>>(part_rs, rowsum);
    rl_final_new<<<1, 512, 0, stream>>>(rowsum, part_ss, sigma, out_RL, out_sigma);
  } else {
    float* rs_old = tail;
    float* ss_old = rs_old + TOPICS;
    row_reduce<<<TOPICS, 256, 0, stream>>>(out_alpha, rs_old, ss_old);
    rl_final_old<<<1, 512, 0, stream>>>(rs_old, ss_old, sigma, out_RL, out_sigma);
  }
}

// Round 11
// 195.038 us; speedup vs baseline: 1.5216x; 1.4581x over previous
//
#include <hip/hip_runtime.h>

#define VOCAB 50000
#define VDIM 256
#define TOPICS 512
#define VT 32
#define NBLK 1563   // ceil(VOCAB/VT)

typedef unsigned int uint;
typedef unsigned short ushort;
using short8 = __attribute__((ext_vector_type(8))) short;
using f32x4  = __attribute__((ext_vector_type(4))) float;

__device__ __forceinline__ ushort bf16_rne(float f) {
  uint u = __float_as_uint(f);
  u += 0x7FFFu + ((u >> 16) & 1u);
  return (ushort)(u >> 16);
}
__device__ __forceinline__ float bf16f(ushort h) {
  return __uint_as_float(((uint)h) << 16);
}
__device__ __forceinline__ uint packbf2(float a, float b) {
  return (uint)bf16_rne(a) | ((uint)bf16_rne(b) << 16);
}

// ---------------------------------------------------------------------------
// Precompute, SINGLE-plane bf16 fragment-major packing (R11):
//   tBp[tile=t>>4][ks=d>>5][lane=(t&15)|(((d>>3)&3)<<4)][e=d&7]   (256 KB)
//   Atp[dtile=d>>4][ks=t>>5][lane=(d&15)|(((t>>3)&3)<<4)][e=t&7]  (256 KB)
// tB/At rounded to bf16 (1 plane): precision carried by W hi/lo split instead.
// ---------------------------------------------------------------------------
__global__ __launch_bounds__(512) void precompute(
    const float* __restrict__ t2v, const float* __restrict__ A,
    const float* __restrict__ B,
    ushort* __restrict__ tBp, ushort* __restrict__ Atp)
{
  __shared__ float row[256];
  const int b = blockIdx.x, tid = threadIdx.x;
  if (b < TOPICS) {
    const int t = b;
    if (tid < 256) row[tid] = t2v[(size_t)t * 256 + tid];
    __syncthreads();
    if (tid < 256) {
      const int d = tid;
      const float4* rv = (const float4*)row;
      const float4* bv = (const float4*)(B + (size_t)d * 256);
      float acc = 0.f;
#pragma unroll 8
      for (int k = 0; k < 64; ++k) {
        float4 r = rv[k], x = bv[k];
        acc += r.x * x.x + r.y * x.y + r.z * x.z + r.w * x.w;
      }
      const int tile = t >> 4, ks = d >> 5;
      const int lane = (t & 15) | (((d >> 3) & 3) << 4);
      const int e = d & 7;
      tBp[((size_t)tile * 8 + ks) * 512 + lane * 8 + e] = bf16_rne(acc);
    }
  } else {
    const int d = b - TOPICS;
    if (tid < 256) row[tid] = A[(size_t)d * 256 + tid];
    __syncthreads();
    const int t = tid;
    const float4* rv = (const float4*)row;
    const float4* tv = (const float4*)(t2v + (size_t)t * 256);
    float acc = 0.f;
#pragma unroll 8
    for (int k = 0; k < 64; ++k) {
      float4 r = rv[k], x = tv[k];
      acc += r.x * x.x + r.y * x.y + r.z * x.z + r.w * x.w;
    }
    const int dtile = d >> 4, ks = t >> 5;
    const int lane = (d & 15) | (((t >> 3) & 3) << 4);
    const int e = t & 7;
    Atp[((size_t)dtile * 16 + ks) * 512 + lane * 8 + e] = bf16_rne(acc);
  }
}

// ---------------------------------------------------------------------------
// Fused main — R8 structure (interleaved regular stores), R11 changes:
//  - single-operand A panels (tB/At bf16): A-load bytes halved
//  - s = tB_bf·W_hi + tB_bf·W_lo (4 MFMA/step); mu = At_bf·pa (2 MFMA/step)
//  - A-ring depth 4 STEPS (32 VGPR, same budget as old depth-2 pairs):
//    prefetch distance doubled at unchanged register pressure
// ---------------------------------------------------------------------------
__global__ __launch_bounds__(256, 4) void fused_main(
    const float* __restrict__ w2v,
    const ushort* __restrict__ tBp, const ushort* __restrict__ Atp,
    const float* __restrict__ sigma,
    float* __restrict__ out_alpha, float* __restrict__ out_P,
    float* __restrict__ out_s,
    float* __restrict__ part_rs, float* __restrict__ part_ss, int do_rl)
{
  __shared__ __align__(16) char smem[33792];
  ushort (*Whi)[264] = (ushort (*)[264])smem;            // 16896 B
  ushort (*Wlo)[264] = (ushort (*)[264])(smem + 16896);  // 16896 B
  ushort (*PA)[520]  = (ushort (*)[520])smem;            // 33280 B (alias, W dead)
  __shared__ float red[4][VT];
  __shared__ float rs_lds[TOPICS];                       // 2 KB rowsum stage

  const int tid  = threadIdx.x;
  const int wave = tid >> 6, lane = tid & 63;
  const int lr = lane & 15, lg = lane >> 4;
  const int vb = blockIdx.x * VT;

  // ---- issue first 4 ring slots (steps 0..3) before W staging ----
  const ushort* sbase = tBp + (size_t)wave * 32768 + lane * 8;
  short8 Ah[4];
#pragma unroll
  for (int i = 0; i < 4; ++i)
    Ah[i] = *(const short8*)(sbase + (size_t)i * 4096);   // n=i: (n&7)*4096+(n>>3)*512

  // ---- stage W hi/lo (32 rows x 256 dims) ----
#pragma unroll
  for (int it = 0; it < 8; ++it) {
    int j = tid + (it << 8);
    int v = j >> 6, q = j & 63;
    int vr = min(vb + v, VOCAB - 1);
    float4 x = *(const float4*)(w2v + (size_t)vr * 256 + (q << 2));
    float xs[4] = {x.x, x.y, x.z, x.w};
    ushort h[4], l[4];
#pragma unroll
    for (int i = 0; i < 4; ++i) {
      ushort hi = bf16_rne(xs[i]);
      h[i] = hi;
      l[i] = bf16_rne(xs[i] - bf16f(hi));
    }
    *(uint2*)&Whi[v][q << 2] = make_uint2((uint)h[0] | ((uint)h[1] << 16),
                                          (uint)h[2] | ((uint)h[3] << 16));
    *(uint2*)&Wlo[v][q << 2] = make_uint2((uint)l[0] | ((uint)l[1] << 16),
                                          (uint)l[2] | ((uint)l[3] << 16));
  }
  __syncthreads();

  // ---- s-GEMM: acc[mi][nj]; ring depth 4 steps, 4 MFMA/step ----
  f32x4 acc[8][2];
#pragma unroll
  for (int mi = 0; mi < 8; ++mi)
#pragma unroll
    for (int nj = 0; nj < 2; ++nj) acc[mi][nj] = (f32x4){0.f, 0.f, 0.f, 0.f};

#pragma unroll
  for (int ks = 0; ks < 8; ++ks) {
    const int k0 = (ks << 5) + (lg << 3);
    short8 bh[2], bl[2];
#pragma unroll
    for (int nj = 0; nj < 2; ++nj) {
      bh[nj] = *(const short8*)&Whi[(nj << 4) + lr][k0];
      bl[nj] = *(const short8*)&Wlo[(nj << 4) + lr][k0];
    }
#pragma unroll
    for (int mi = 0; mi < 8; ++mi) {
      const int n = (ks << 3) + mi;
      short8 ah = Ah[n & 3];
      if (n + 4 < 64) {
        const int n4 = n + 4;
        Ah[n & 3] = *(const short8*)(sbase + (size_t)(n4 & 7) * 4096
                                           + (size_t)(n4 >> 3) * 512);
      }
#pragma unroll
      for (int nj = 0; nj < 2; ++nj) {
        acc[mi][nj] = __builtin_amdgcn_mfma_f32_16x16x32_bf16(ah, bh[nj], acc[mi][nj], 0, 0, 0);
        acc[mi][nj] = __builtin_amdgcn_mfma_f32_16x16x32_bf16(ah, bl[nj], acc[mi][nj], 0, 0, 0);
      }
    }
  }

  // ---- write s (D layout: col = lr, row = lg*4 + r) ----
#pragma unroll
  for (int mi = 0; mi < 8; ++mi) {
    const int t = (wave << 7) + (mi << 4) + (lg << 2);
#pragma unroll
    for (int r = 0; r < 4; ++r)
#pragma unroll
      for (int nj = 0; nj < 2; ++nj) {
        const int v = vb + (nj << 4) + lr;
        if (v < VOCAB) out_s[(size_t)(t + r) * VOCAB + v] = acc[mi][nj][r];
      }
  }

  // ---- softmax over t per column ----
  float gmax[2];
  {
    float pm[2] = {-3.4e38f, -3.4e38f};
#pragma unroll
    for (int mi = 0; mi < 8; ++mi)
#pragma unroll
      for (int nj = 0; nj < 2; ++nj)
#pragma unroll
        for (int r = 0; r < 4; ++r) pm[nj] = fmaxf(pm[nj], acc[mi][nj][r]);
#pragma unroll
    for (int nj = 0; nj < 2; ++nj) {
      pm[nj] = fmaxf(pm[nj], __shfl_xor(pm[nj], 16));
      pm[nj] = fmaxf(pm[nj], __shfl_xor(pm[nj], 32));
    }
    if (lg == 0) { red[wave][lr] = pm[0]; red[wave][16 + lr] = pm[1]; }
  }
  __syncthreads();
#pragma unroll
  for (int nj = 0; nj < 2; ++nj) {
    const int c = (nj << 4) + lr;
    gmax[nj] = fmaxf(fmaxf(red[0][c], red[1][c]), fmaxf(red[2][c], red[3][c]));
  }
  __syncthreads();

  // ---- issue first 4 mu ring slots (steps 0..3); hide under exp pass ----
  const ushort* mbase = Atp + (size_t)wave * 32768 + lane * 8;
  short8 Mh[4];
#pragma unroll
  for (int i = 0; i < 4; ++i)
    Mh[i] = *(const short8*)(mbase + (size_t)i * 8192);   // n=i: (n&3)*8192+(n>>2)*512

  float inv[2];
  {
    float ps[2] = {0.f, 0.f};
#pragma unroll
    for (int mi = 0; mi < 8; ++mi)
#pragma unroll
      for (int nj = 0; nj < 2; ++nj)
#pragma unroll
        for (int r = 0; r < 4; ++r) {
          float e = __expf(acc[mi][nj][r] - gmax[nj]);
          acc[mi][nj][r] = e;
          ps[nj] += e;
        }
#pragma unroll
    for (int nj = 0; nj < 2; ++nj) {
      ps[nj] += __shfl_xor(ps[nj], 16);
      ps[nj] += __shfl_xor(ps[nj], 32);
    }
    if (lg == 0) { red[wave][lr] = ps[0]; red[wave][16 + lr] = ps[1]; }
  }
  __syncthreads();
#pragma unroll
  for (int nj = 0; nj < 2; ++nj) {
    const int c = (nj << 4) + lr;
    inv[nj] = 1.0f / (red[0][c] + red[1][c] + red[2][c] + red[3][c]);
  }
  __syncthreads();   // red reads done; last Whi/Wlo reads were in s-loop

  // ---- alpha = exp*inv: fp32 to global, bf16 to LDS (PA aliases W),
  //      rowsum partials into rs_lds (no global scatter) ----
  float ssq = 0.f;
#pragma unroll
  for (int mi = 0; mi < 8; ++mi) {
    const int tb = (wave << 7) + (mi << 4) + (lg << 2);
#pragma unroll
    for (int nj = 0; nj < 2; ++nj) {
#pragma unroll
      for (int r = 0; r < 4; ++r) acc[mi][nj][r] *= inv[nj];
      const int v = vb + (nj << 4) + lr;
      if (v < VOCAB) {
#pragma unroll
        for (int r = 0; r < 4; ++r)
          out_alpha[(size_t)(tb + r) * VOCAB + v] = acc[mi][nj][r];
      }
      uint2 pw;
      pw.x = packbf2(acc[mi][nj][0], acc[mi][nj][1]);
      pw.y = packbf2(acc[mi][nj][2], acc[mi][nj][3]);
      *(uint2*)&PA[(nj << 4) + lr][tb] = pw;
    }
    if (do_rl) {
#pragma unroll
      for (int r = 0; r < 4; ++r) {
        float rowp = 0.f;
#pragma unroll
        for (int nj = 0; nj < 2; ++nj) {
          float a = acc[mi][nj][r];
          float am = (vb + (nj << 4) + lr < VOCAB) ? a : 0.f;
          rowp += am;
          ssq = fmaf(am, am, ssq);
        }
        rowp += __shfl_xor(rowp, 1);
        rowp += __shfl_xor(rowp, 2);
        rowp += __shfl_xor(rowp, 4);
        rowp += __shfl_xor(rowp, 8);
        if (lr == 0) rs_lds[tb + r] = rowp;
      }
    }
  }
  __syncthreads();

  // ---- mu-GEMM: ring depth 4 steps, 2 MFMA/step ----
  f32x4 macc[4][2];
#pragma unroll
  for (int mi = 0; mi < 4; ++mi)
#pragma unroll
    for (int nj = 0; nj < 2; ++nj) macc[mi][nj] = (f32x4){0.f, 0.f, 0.f, 0.f};

#pragma unroll
  for (int ks = 0; ks < 16; ++ks) {
    const int k0 = (ks << 5) + (lg << 3);
    short8 pb[2];
#pragma unroll
    for (int nj = 0; nj < 2; ++nj)
      pb[nj] = *(const short8*)&PA[(nj << 4) + lr][k0];
#pragma unroll
    for (int mi = 0; mi < 4; ++mi) {
      const int n = (ks << 2) + mi;
      short8 ah = Mh[n & 3];
      if (n + 4 < 64) {
        const int n4 = n + 4;
        Mh[n & 3] = *(const short8*)(mbase + (size_t)(n4 & 3) * 8192
                                           + (size_t)(n4 >> 2) * 512);
      }
#pragma unroll
      for (int nj = 0; nj < 2; ++nj)
        macc[mi][nj] = __builtin_amdgcn_mfma_f32_16x16x32_bf16(ah, pb[nj], macc[mi][nj], 0, 0, 0);
    }
  }

  // ---- P: sum_d (w2v - mu)^2 per column (w2v re-read from global/L2) ----
  {
    float pp[2] = {0.f, 0.f};
#pragma unroll
    for (int mi = 0; mi < 4; ++mi) {
      const int dbase = (wave << 6) + (mi << 4) + (lg << 2);
#pragma unroll
      for (int nj = 0; nj < 2; ++nj) {
        const int vr = min(vb + (nj << 4) + lr, VOCAB - 1);
        float4 w = *(const float4*)(w2v + (size_t)vr * 256 + dbase);
        float d0 = w.x - macc[mi][nj][0];
        float d1 = w.y - macc[mi][nj][1];
        float d2 = w.z - macc[mi][nj][2];
        float d3 = w.w - macc[mi][nj][3];
        pp[nj] += d0 * d0 + d1 * d1 + d2 * d2 + d3 * d3;
      }
    }
#pragma unroll
    for (int nj = 0; nj < 2; ++nj) {
      pp[nj] += __shfl_xor(pp[nj], 16);
      pp[nj] += __shfl_xor(pp[nj], 32);
    }
    if (lg == 0) { red[wave][lr] = pp[0]; red[wave][16 + lr] = pp[1]; }
  }
  __syncthreads();
  if (tid < VT) {
    float sum = red[0][tid] + red[1][tid] + red[2][tid] + red[3][tid];
    const int v = vb + tid;
    if (v < VOCAB) out_P[v] = sum / sigma[0];
  }

  // ---- coalesced part_rs block store (2KB contiguous) + ssq ----
  if (do_rl) {
    part_rs[(size_t)blockIdx.x * TOPICS + tid]       = rs_lds[tid];
    part_rs[(size_t)blockIdx.x * TOPICS + 256 + tid] = rs_lds[256 + tid];
    ssq += __shfl_xor(ssq, 1);
    ssq += __shfl_xor(ssq, 2);
    ssq += __shfl_xor(ssq, 4);
    ssq += __shfl_xor(ssq, 8);
    ssq += __shfl_xor(ssq, 16);
    ssq += __shfl_xor(ssq, 32);
    if (lane == 0) part_ss[blockIdx.x * 4 + wave] = ssq;
  }
}

// ---------------------------------------------------------------------------
// RL pass 2: rowsum[t] = sum_blk part_rs[blk][t]. One block per topic.
// ---------------------------------------------------------------------------
__global__ __launch_bounds__(256) void rl_pass2(
    const float* __restrict__ part_rs, float* __restrict__ rowsum)
{
  const int t = blockIdx.x;
  float s = 0.f;
  for (int i = threadIdx.x; i < NBLK; i += 256)
    s += part_rs[(size_t)i * TOPICS + t];
  __shared__ float lsum[4];
  const int lane = threadIdx.x & 63, wave = threadIdx.x >> 6;
#pragma unroll
  for (int off = 32; off > 0; off >>= 1) s += __shfl_xor(s, off);
  if (lane == 0) lsum[wave] = s;
  __syncthreads();
  if (threadIdx.x == 0) rowsum[t] = lsum[0] + lsum[1] + lsum[2] + lsum[3];
}

// RL finalize: RL = sum part_ss - sum_t rowsum^2 / VOCAB
__global__ __launch_bounds__(512) void rl_final_new(
    const float* __restrict__ rowsum, const float* __restrict__ part_ss,
    const float* __restrict__ sigma, float* __restrict__ out_RL,
    float* __restrict__ out_sigma)
{
  const int t = threadIdx.x;
  float b = rowsum[t] * rowsum[t];
  float a = 0.f;
  for (int i = t; i < NBLK * 4; i += 512) a += part_ss[i];
  __shared__ float la[8], lb[8];
  const int lane = t & 63, wave = t >> 6;
#pragma unroll
  for (int off = 32; off > 0; off >>= 1) {
    a += __shfl_xor(a, off);
    b += __shfl_xor(b, off);
  }
  if (lane == 0) { la[wave] = a; lb[wave] = b; }
  __syncthreads();
  if (t == 0) {
    float sa = 0.f, sb = 0.f;
#pragma unroll
    for (int w = 0; w < 8; ++w) { sa += la[w]; sb += lb[w]; }
    out_RL[0] = sa - sb / (float)VOCAB;
    out_sigma[0] = sigma[0];
  }
}

// ---------------------------------------------------------------------------
// Fallback (small ws): old alpha re-read path
// ---------------------------------------------------------------------------
__global__ __launch_bounds__(256) void row_reduce(
    const float* __restrict__ alpha, float* __restrict__ rowsum, float* __restrict__ ssum)
{
  const int t = blockIdx.x;
  const float4* base = (const float4*)(alpha + (size_t)t * VOCAB);
  float rs = 0.f, ss = 0.f;
  for (int i = threadIdx.x; i < VOCAB / 4; i += 256) {
    float4 a = base[i];
    rs += a.x + a.y + a.z + a.w;
    ss += a.x * a.x + a.y * a.y + a.z * a.z + a.w * a.w;
  }
  __shared__ float lr[4], ls[4];
  const int lane = threadIdx.x & 63, wave = threadIdx.x >> 6;
#pragma unroll
  for (int off = 32; off > 0; off >>= 1) {
    rs += __shfl_xor(rs, off);
    ss += __shfl_xor(ss, off);
  }
  if (lane == 0) { lr[wave] = rs; ls[wave] = ss; }
  __syncthreads();
  if (threadIdx.x == 0) {
    rowsum[t] = lr[0] + lr[1] + lr[2] + lr[3];
    ssum[t]   = ls[0] + ls[1] + ls[2] + ls[3];
  }
}

__global__ __launch_bounds__(512) void rl_final_old(
    const float* __restrict__ rowsum, const float* __restrict__ ssum,
    const float* __restrict__ sigma, float* __restrict__ out_RL,
    float* __restrict__ out_sigma)
{
  const int t = threadIdx.x;
  float a = ssum[t];
  float b = rowsum[t] * rowsum[t];
  __shared__ float la[8], lb[8];
  const int lane = t & 63, wave = t >> 6;
#pragma unroll
  for (int off = 32; off > 0; off >>= 1) {
    a += __shfl_xor(a, off);
    b += __shfl_xor(b, off);
  }
  if (lane == 0) { la[wave] = a; lb[wave] = b; }
  __syncthreads();
  if (t == 0) {
    float sa = 0.f, sb = 0.f;
#pragma unroll
    for (int w = 0; w < 8; ++w) { sa += la[w]; sb += lb[w]; }
    out_RL[0] = sa - sb / (float)VOCAB;
    out_sigma[0] = sigma[0];
  }
}

extern "C" void kernel_launch(void* const* d_in, const int* in_sizes, int n_in,
                              void* d_out, int out_size, void* d_ws, size_t ws_size,
                              hipStream_t stream) {
  const float* w2v   = (const float*)d_in[0];  // [50000][256]
  const float* t2v   = (const float*)d_in[1];  // [512][256]
  const float* A     = (const float*)d_in[2];  // [256][256]
  const float* B     = (const float*)d_in[3];  // [256][256]
  const float* sigma = (const float*)d_in[4];  // [1]

  float* out       = (float*)d_out;
  float* out_alpha = out;                                  // 25,600,000
  float* out_P     = out + (size_t)TOPICS * VOCAB;         // 50,000
  float* out_RL    = out_P + VOCAB;                        // 1
  float* out_s     = out_RL + 1;                           // 25,600,000
  float* out_sigma = out_s + (size_t)TOPICS * VOCAB;       // 1

  ushort* tBp = (ushort*)d_ws;                             // 131072 ushorts (256 KB)
  ushort* Atp = tBp + (size_t)131072;                      // 131072 ushorts (256 KB)
  float* tail = (float*)(Atp + (size_t)131072);            // after 512 KiB
  float* part_rs = tail;                                   // [NBLK][512]
  float* part_ss = part_rs + (size_t)NBLK * TOPICS;        // 1563*4
  float* rowsum  = part_ss + (size_t)NBLK * 4;             // 512
  size_t need = (size_t)(2 * 131072) * 2 +
                ((size_t)NBLK * TOPICS + (size_t)NBLK * 4 + TOPICS) * 4;
  const int do_rl = (ws_size >= need) ? 1 : 0;

  precompute<<<TOPICS + VDIM, 512, 0, stream>>>(t2v, A, B, tBp, Atp);

  fused_main<<<NBLK, 256, 0, stream>>>(w2v, tBp, Atp, sigma,
                                       out_alpha, out_P, out_s,
                                       part_rs, part_ss, do_rl);

  if (do_rl) {
    rl_pass2<<<TOPICS, 256, 0, stream>>>(part_rs, rowsum);
    rl_final_new<<<1, 512, 0, stream>>>(rowsum, part_ss, sigma, out_RL, out_sigma);
  } else {
    float* rs_old = tail;
    float* ss_old = rs_old + TOPICS;
    row_reduce<<<TOPICS, 256, 0, stream>>>(out_alpha, rs_old, ss_old);
    rl_final_old<<<1, 512, 0, stream>>>(rs_old, ss_old, sigma, out_RL, out_sigma);
  }
}